// Round 12
// baseline (253.533 us; speedup 1.0000x reference)
//
#include <hip/hip_runtime.h>
#include <hip/hip_bf16.h>
#include <math.h>

typedef __attribute__((ext_vector_type(4))) short short4v;
typedef __attribute__((ext_vector_type(8))) short short8;
typedef __attribute__((ext_vector_type(4))) float f32x4;
typedef __attribute__((ext_vector_type(2))) float f32x2;
typedef _Float16 half8 __attribute__((ext_vector_type(8)));

#define BATCH   4096
#define XLEN    1008
#define NOC1    128
#define NPOS    32
#define NOC2    256
#define NQ      9
#define NCAPS   288
#define NDIM    8

// ws layout (bytes)
#define BWH_OFF   0           // wavelet B-pack fp16, 128 KB
#define BPH_OFF   131072      // conv2 B-pack fp16, 1 MB
#define U_OFF     1179648     // u fp32 [b][288][8], 37.75 MB (h2 eliminated)

static __device__ __forceinline__ short f2h(float v) {
    _Float16 h = (_Float16)v;
    return *reinterpret_cast<short*>(&h);
}

// packed fp32 fma on batch-pairs: a (splat) * b + c  ->  v_pk_fma_f32
static __device__ __forceinline__ f32x2 pkfma(float a, f32x2 b, f32x2 c) {
    f32x2 av = {a, a};
    return av * b + c;    // clang: llvm.fmuladd<2 x float> -> v_pk_fma_f32
}

// DPP 16-lane (row) sum — VALU pipe. Bitwise == shfl_xor 1/2/4/8 tree.
template <int CTRL>
static __device__ __forceinline__ float dpp_addf(float x) {
    int y = __builtin_amdgcn_update_dpp(0, __builtin_bit_cast(int, x),
                                        CTRL, 0xf, 0xf, true);
    return x + __builtin_bit_cast(float, y);
}
static __device__ __forceinline__ float rowsum16(float x) {
    x = dpp_addf<0xB1>(x);    // quad_perm xor1
    x = dpp_addf<0x4E>(x);    // quad_perm xor2
    x = dpp_addf<0x141>(x);   // row_half_mirror
    x = dpp_addf<0x140>(x);   // row_mirror
    return x;
}

// A-LDS swizzle: folds BOTH row>>5 (batch) and (row>>2)&3 (rg at write time)
// into the 16B-slot index. R11's chunk^(row>>5) left all 4 rg-groups on the
// same banks during the phase-1c scalar writes -> 6.9M bank conflicts.
static __device__ __forceinline__ int aslot(int row, int chunk) {
    return (chunk ^ ((row >> 5) & 7) ^ (((row >> 2) & 3) << 2)) & 15;
}

// ---------------- K1: fused weight packing (wavelet + conv2), fp16 ---------
__global__ __launch_bounds__(256) void k_pack(const float* __restrict__ a,
                                              const float* __restrict__ w,
                                              const float* __restrict__ cw,
                                              short* __restrict__ bwh,
                                              short* __restrict__ bph) {
    int bid = blockIdx.x;
    int tid = threadIdx.x;
    if (bid < 256) {
        int idx = bid * 256 + tid;            // 65536 wavelet elems
        int e    = idx & 7;
        int lane = (idx >> 3) & 63;
        int s    = (idx >> 9) & 15;
        int nt   = idx >> 13;
        int oc = nt * 16 + (lane & 15);
        int k  = s * 32 + (lane >> 4) * 8 + e;
        float t  = -1.0f + 2.0f * (float)k / 511.0f;
        float av = fmaxf(a[oc], 1e-5f);
        float ts = t / av;
        bwh[idx] = f2h(cosf(w[oc] * t) * expf(-0.5f * ts * ts));
    } else {
        int o = (bid - 256) * 256 + tid;      // 524288 conv2 elems
        int e    = o & 7;
        int lane = (o >> 3) & 63;
        int s    = (o >> 9) & 63;
        int nt   = o >> 15;
        int n  = nt * 16 + (lane & 15);
        int j  = lane >> 4;
        int kk = s >> 2;
        int ic = (s & 3) * 32 + j * 8 + e;
        bph[o] = f2h(cw[(n * NOC1 + ic) * 16 + kk]);
    }
}

// ---------------- K2: FUSED WavConv + PrimaryCaps conv ---------------------
// h2 never touches HBM (R11: FETCH 39->15 MB, WRITE 55->37 MB confirmed).
// R12 fix: aslot() swizzle on both the phase-1c acc->LDS write and the
// phase-2 read; (row>>2)&3 == rg at write time separates the rg-groups'
// banks (R11: 6.9M conflicts from 8-way-serialized b16 writes).
__global__ __launch_bounds__(512, 2) void k_wavcaps(
        const float* __restrict__ x,
        const short* __restrict__ bwh,
        const short* __restrict__ bph,
        const float* __restrict__ cb,
        float* __restrict__ u) {
    __shared__ char smem[66048];         // A: 258 rows x 256 B; xl+p_lds overlay
    short* Ald   = (short*)smem;         // swizzled [row][16B-slot]
    short* xl    = (short*)smem;         // [8][1512] overlay (dead before A writes)
    float* p_lds = (float*)smem;         // [8 b][1152] overlay (after conv loop)

    int tid  = threadIdx.x;
    int w    = tid >> 6;     // phase1: batch 0..7; phase2: oc-half quarter
    int lane = tid & 63;
    int col  = lane & 15;
    int rg   = lane >> 4;
    int b0   = blockIdx.x * 8;

    // ---- phase 1a: stage x -> xl fp16 (24 KB) ----
    for (int i4 = tid; i4 < 2016; i4 += 512) {
        int b  = i4 / 252;
        int e4 = i4 - b * 252;
        float4 v = *(const float4*)(x + (size_t)(b0 + b) * XLEN + e4 * 4);
        int i    = e4 * 4;
        int slot = i + 8 * (i >> 4);
        short4v hv;
        hv.x = f2h(v.x); hv.y = f2h(v.y); hv.z = f2h(v.z); hv.w = f2h(v.w);
        *(short4v*)&xl[(size_t)b * 1512 + slot] = hv;
    }
    __syncthreads();

    // ---- phase 1b: wavconv MFMA (R8 retile: wave w owns batch w) ----
    {
        f32x4 acc[2][8];
        f32x4 z = {0.f, 0.f, 0.f, 0.f};
#pragma unroll
        for (int tl = 0; tl < 2; ++tl)
#pragma unroll
            for (int nt = 0; nt < 8; ++nt) acc[tl][nt] = z;

        for (int s = 0; s < 16; ++s) {
            half8 Bh[8];
#pragma unroll
            for (int nt = 0; nt < 8; ++nt) {
                size_t off = ((size_t)(nt * 16 + s) * 64 + lane) * 8;
                Bh[nt] = __builtin_bit_cast(half8, *(const short8*)(bwh + off));
            }
#pragma unroll
            for (int tl = 0; tl < 2; ++tl) {
                int pos  = tl * 16 + col;
                int i    = (pos + 2 * s) * 16 + rg * 8;
                int slot = i + 8 * (i >> 4);
                half8 ah = __builtin_bit_cast(half8, *(const short8*)&xl[(size_t)w * 1512 + slot]);
#pragma unroll
                for (int nt = 0; nt < 8; ++nt)
                    acc[tl][nt] = __builtin_amdgcn_mfma_f32_16x16x32_f16(ah, Bh[nt], acc[tl][nt], 0, 0, 0);
            }
        }
        __syncthreads();    // xl dead; A may overlay it now

        // ---- phase 1c: acc -> swizzled A-LDS ----
        // row = w*32 + tl*16 + rg*4 + r  ->  (row>>5)&7 == w, (row>>2)&3 == rg
#pragma unroll
        for (int tl = 0; tl < 2; ++tl)
#pragma unroll
            for (int nt = 0; nt < 8; ++nt)
#pragma unroll
                for (int r = 0; r < 4; ++r) {
                    int pos  = tl * 16 + rg * 4 + r;
                    int row  = w * 32 + pos;
                    int oc   = nt * 16 + col;
                    int slot = aslot(row, oc >> 3);
                    Ald[row * 128 + slot * 8 + (oc & 7)] = f2h(acc[tl][nt][r]);
                }
        if (tid < 32) {                          // zero guard rows 256,257
            short8 zz = {0, 0, 0, 0, 0, 0, 0, 0};
            *(short8*)&Ald[4096 * 8 + tid * 8] = zz;
        }
    }
    __syncthreads();

    // ---- phase 2: conv main loop (R4 core, aslot read) ----
    f32x4 acc[5][2];
    f32x4 z = {0.f, 0.f, 0.f, 0.f};
#pragma unroll
    for (int mt = 0; mt < 5; ++mt) { acc[mt][0] = z; acc[mt][1] = z; }

    int rowb[5];
#pragma unroll
    for (int mt = 0; mt < 5; ++mt) {
        int m = mt * 16 + col;
        rowb[mt] = (m & 7) * 32 + 2 * (m >> 3);
    }

    for (int s = 0; s < 64; ++s) {
        int kk    = s >> 2;
        int icb8  = (s & 3) * 4;                 // base 16B-slot
        short8 ar[5];
#pragma unroll
        for (int mt = 0; mt < 5; ++mt) {
            int row  = rowb[mt] + kk;
            int slot = aslot(row, icb8 + rg);
            ar[mt] = *(const short8*)&Ald[row * 128 + slot * 8];
        }
#pragma unroll
        for (int n = 0; n < 2; ++n) {
            size_t bo = ((size_t)((w + n * 8) * 64 + s) * 64 + lane) * 8;
            half8 Bh = __builtin_bit_cast(half8, *(const short8*)(bph + bo));
#pragma unroll
            for (int mt = 0; mt < 5; ++mt)
                acc[mt][n] = __builtin_amdgcn_mfma_f32_16x16x32_f16(
                    __builtin_bit_cast(half8, ar[mt]), Bh, acc[mt][n], 0, 0, 0);
        }
    }
    __syncthreads();    // all A reads done before p_lds overlays the buffer

    int oc2l = w * 16 + col;                  // 0..127 within half
    for (int n = 0; n < 2; ++n) {
        float bias = cb[n * 128 + oc2l];
#pragma unroll
        for (int mt = 0; mt < 5; ++mt)
#pragma unroll
            for (int r = 0; r < 4; ++r) {
                int m = mt * 16 + rg * 4 + r;
                if (m < 72)
                    p_lds[(m & 7) * 1152 + oc2l * 9 + (m >> 3)] = acc[mt][n][r] + bias;
            }
        __syncthreads();
        for (int idx = tid; idx < 1152; idx += 512) {   // 8 b x 144 caps
            int lb = idx / 144;
            int cl = idx - lb * 144;
            float* ppt = &p_lds[lb * 1152 + cl * 8];
            float sn = 0.f;
#pragma unroll
            for (int i = 0; i < NDIM; ++i) sn = fmaf(ppt[i], ppt[i], sn);
            float sc = sn / (1.f + sn) / sqrtf(sn + 1e-8f);
            float* ug = u + ((size_t)(b0 + lb) * (NCAPS * NDIM) + (n * 144 + cl) * 8);
            float4 u0 = make_float4(ppt[0] * sc, ppt[1] * sc, ppt[2] * sc, ppt[3] * sc);
            float4 u1 = make_float4(ppt[4] * sc, ppt[5] * sc, ppt[6] * sc, ppt[7] * sc);
            ((float4*)ug)[0] = u0;
            ((float4*)ug)[1] = u1;
        }
        __syncthreads();
    }
}

// ---------------- K4: u_hat + routing, 2 batches/block, 1024 threads -------
// R1 version (proven 92.5 us, VGPR 32, no spill). LOCKED: R2 (scalar uh)
// scratch-spilled (+65MB writes); R6 (LDS atomicAdd) serialized on the LDS
// atomic unit (+50us); R9 (u transpose) 5x'd HBM fetch (299MB).
__global__ __launch_bounds__(1024, 8) void k_routing(const float* __restrict__ u,
                                                     const float* __restrict__ Wc,
                                                     float* __restrict__ out) {
    __shared__ float b_lds[2][NCAPS * 4];     // 9216 B
    __shared__ float c_lds[2][NCAPS * 4];     // 9216 B
    __shared__ float part_lds[2][1024];       // 8192 B
    __shared__ float v_lds[2][64];            // 512 B

    int tid = threadIdx.x;
    int b0  = blockIdx.x * 2;

    int g = tid >> 6;        // 0..15
    int l = tid & 63;
    int d = l >> 4;
    int o = l & 15;
    int gu = __builtin_amdgcn_readfirstlane(g);   // wave-uniform -> s_load for u

    const float* ub0 = u + (size_t)(b0 + 0) * (NCAPS * NDIM) + gu * 18 * NDIM;
    const float* ub1 = u + (size_t)(b0 + 1) * (NCAPS * NDIM) + gu * 18 * NDIM;

    f32x2 uh[18];
#pragma unroll
    for (int c = 0; c < 18; ++c) {
        int cap = gu * 18 + c;
        const float4* W4 = (const float4*)(Wc + ((size_t)cap * 512) + l * 8);
        float4 A  = W4[0];
        float4 Bv = W4[1];
        f32x2 u0 = {ub0[c * 8 + 0], ub1[c * 8 + 0]};
        f32x2 u1 = {ub0[c * 8 + 1], ub1[c * 8 + 1]};
        f32x2 u2 = {ub0[c * 8 + 2], ub1[c * 8 + 2]};
        f32x2 u3 = {ub0[c * 8 + 3], ub1[c * 8 + 3]};
        f32x2 u4 = {ub0[c * 8 + 4], ub1[c * 8 + 4]};
        f32x2 u5 = {ub0[c * 8 + 5], ub1[c * 8 + 5]};
        f32x2 u6 = {ub0[c * 8 + 6], ub1[c * 8 + 6]};
        f32x2 u7 = {ub0[c * 8 + 7], ub1[c * 8 + 7]};
        f32x2 t = (f32x2){A.x, A.x} * u0;
        t = pkfma(A.y,  u1, t);
        t = pkfma(A.z,  u2, t);
        t = pkfma(A.w,  u3, t);
        t = pkfma(Bv.x, u4, t);
        t = pkfma(Bv.y, u5, t);
        t = pkfma(Bv.z, u6, t);
        t = pkfma(Bv.w, u7, t);
        uh[c] = t;
    }

    for (int r = 0; r < 3; ++r) {
        if (r > 0) {
            __builtin_amdgcn_wave_barrier();
            for (int i = l; i < 36; i += 64) {       // 2 batches x 18 caps
                int bb = (i >= 18) ? 1 : 0;
                int cl = i - bb * 18;
                int c  = gu * 18 + cl;
                float4 bv = *(const float4*)&b_lds[bb][c * 4];
                float m  = fmaxf(fmaxf(bv.x, bv.y), fmaxf(bv.z, bv.w));
                float e0 = expf(bv.x - m), e1 = expf(bv.y - m);
                float e2 = expf(bv.z - m), e3 = expf(bv.w - m);
                float inv = 1.f / (e0 + e1 + e2 + e3);
                e0 *= inv; e1 *= inv; e2 *= inv; e3 *= inv;
                *(float4*)&c_lds[bb][c * 4] = make_float4(e0, e1, e2, e3);
                if (r == 2) {
                    *(float4*)(out + 16384 + ((size_t)(b0 + bb) * NCAPS + c) * 4) =
                        make_float4(e0, e1, e2, e3);
                }
            }
            __builtin_amdgcn_wave_barrier();
        }

        f32x2 p = {0.f, 0.f};
        if (r == 0) {
#pragma unroll
            for (int c = 0; c < 18; ++c)
                p = pkfma(0.25f, uh[c], p);
        } else {
#pragma unroll
            for (int c = 0; c < 18; ++c) {
                f32x2 c2 = {c_lds[0][(g * 18 + c) * 4 + d],
                            c_lds[1][(g * 18 + c) * 4 + d]};
                p = c2 * uh[c] + p;    // v_pk_fma_f32
            }
        }
        part_lds[0][tid] = p.x;
        part_lds[1][tid] = p.y;
        __syncthreads();

        if (tid < 128) {
            int bb = tid >> 6;
            int ll = tid & 63;
            float sv = 0.f;
#pragma unroll
            for (int k = 0; k < 16; ++k) sv += part_lds[bb][ll + 64 * k];
            float sq = rowsum16(sv * sv);
            float sc = sq / (1.f + sq) / sqrtf(sq + 1e-8f);
            float v  = sv * sc;
            v_lds[bb][ll] = v;
            if (r == 2) {
                float vv = rowsum16(v * v);
                if ((ll & 15) == 0)
                    out[(size_t)(b0 + bb) * 4 + (ll >> 4)] = sqrtf(vv);
            }
        }
        __syncthreads();

        if (r < 2) {
            f32x2 v01 = {v_lds[0][l], v_lds[1][l]};
#pragma unroll
            for (int c = 0; c < 18; ++c) {
                f32x2 t2 = uh[c] * v01;    // packed mul
                float t0 = rowsum16(t2.x);
                float t1 = rowsum16(t2.y);
                if (o == 0) {
                    if (r == 0) {
                        b_lds[0][(g * 18 + c) * 4 + d] = t0;
                        b_lds[1][(g * 18 + c) * 4 + d] = t1;
                    } else {
                        b_lds[0][(g * 18 + c) * 4 + d] += t0;
                        b_lds[1][(g * 18 + c) * 4 + d] += t1;
                    }
                }
            }
        }
    }
}

extern "C" void kernel_launch(void* const* d_in, const int* in_sizes, int n_in,
                              void* d_out, int out_size, void* d_ws, size_t ws_size,
                              hipStream_t stream) {
    const float* x      = (const float*)d_in[0];
    const float* a      = (const float*)d_in[1];
    const float* w      = (const float*)d_in[2];
    const float* conv_w = (const float*)d_in[3];
    const float* conv_b = (const float*)d_in[4];
    const float* W_caps = (const float*)d_in[5];
    float* out = (float*)d_out;
    char* ws   = (char*)d_ws;

    short*  bwh = (short*)(ws + BWH_OFF);
    short*  bph = (short*)(ws + BPH_OFF);
    float*  u   = (float*)(ws + U_OFF);

    k_pack<<<2304, 256, 0, stream>>>(a, w, conv_w, bwh, bph);
    k_wavcaps<<<BATCH / 8, 512, 0, stream>>>(x, bwh, bph, conv_b, u);
    k_routing<<<BATCH / 2, 1024, 0, stream>>>(u, W_caps, out);
}

// Round 13
// 252.137 us; speedup vs baseline: 1.0055x; 1.0055x over previous
//
#include <hip/hip_runtime.h>
#include <hip/hip_bf16.h>
#include <math.h>

typedef __attribute__((ext_vector_type(4))) short short4v;
typedef __attribute__((ext_vector_type(8))) short short8;
typedef __attribute__((ext_vector_type(4))) float f32x4;
typedef __attribute__((ext_vector_type(2))) float f32x2;
typedef _Float16 half8 __attribute__((ext_vector_type(8)));

#define BATCH   4096
#define XLEN    1008
#define NOC1    128
#define NPOS    32
#define NOC2    256
#define NQ      9
#define NCAPS   288
#define NDIM    8

// ws layout (bytes)
#define BWH_OFF   0           // wavelet B-pack fp16, 128 KB
#define BPH_OFF   131072      // conv2 B-pack fp16, 1 MB
#define U_OFF     1179648     // u fp32 [b][288][8], 37.75 MB (h2 eliminated)

static __device__ __forceinline__ short f2h(float v) {
    _Float16 h = (_Float16)v;
    return *reinterpret_cast<short*>(&h);
}

// packed fp32 fma on batch-pairs: a (splat) * b + c  ->  v_pk_fma_f32
static __device__ __forceinline__ f32x2 pkfma(float a, f32x2 b, f32x2 c) {
    f32x2 av = {a, a};
    return av * b + c;    // clang: llvm.fmuladd<2 x float> -> v_pk_fma_f32
}

// DPP 16-lane (row) sum — VALU pipe. Bitwise == shfl_xor 1/2/4/8 tree.
template <int CTRL>
static __device__ __forceinline__ float dpp_addf(float x) {
    int y = __builtin_amdgcn_update_dpp(0, __builtin_bit_cast(int, x),
                                        CTRL, 0xf, 0xf, true);
    return x + __builtin_bit_cast(float, y);
}
static __device__ __forceinline__ float rowsum16(float x) {
    x = dpp_addf<0xB1>(x);    // quad_perm xor1
    x = dpp_addf<0x4E>(x);    // quad_perm xor2
    x = dpp_addf<0x141>(x);   // row_half_mirror
    x = dpp_addf<0x140>(x);   // row_mirror
    return x;
}

// A-LDS swizzle. Write side (phase 1c, transposed acc): row&15 = col varies
// per lane -> spans all 8 bank groups; (row>>5)=w uniform. Read side
// (phase 2): (row>>5)&7 = col&7 varies per lane (the proven R4 pattern);
// row&15 is near-uniform. XOR of both covers both access patterns.
static __device__ __forceinline__ int aslot(int row, int chunk) {
    return (chunk ^ ((row >> 5) & 7) ^ (row & 15)) & 15;
}

// ---------------- K1: fused weight packing (wavelet + conv2), fp16 ---------
__global__ __launch_bounds__(256) void k_pack(const float* __restrict__ a,
                                              const float* __restrict__ w,
                                              const float* __restrict__ cw,
                                              short* __restrict__ bwh,
                                              short* __restrict__ bph) {
    int bid = blockIdx.x;
    int tid = threadIdx.x;
    if (bid < 256) {
        int idx = bid * 256 + tid;            // 65536 wavelet elems
        int e    = idx & 7;
        int lane = (idx >> 3) & 63;
        int s    = (idx >> 9) & 15;
        int nt   = idx >> 13;
        int oc = nt * 16 + (lane & 15);
        int k  = s * 32 + (lane >> 4) * 8 + e;
        float t  = -1.0f + 2.0f * (float)k / 511.0f;
        float av = fmaxf(a[oc], 1e-5f);
        float ts = t / av;
        bwh[idx] = f2h(cosf(w[oc] * t) * expf(-0.5f * ts * ts));
    } else {
        int o = (bid - 256) * 256 + tid;      // 524288 conv2 elems
        int e    = o & 7;
        int lane = (o >> 3) & 63;
        int s    = (o >> 9) & 63;
        int nt   = o >> 15;
        int n  = nt * 16 + (lane & 15);
        int j  = lane >> 4;
        int kk = s >> 2;
        int ic = (s & 3) * 32 + j * 8 + e;
        bph[o] = f2h(cw[(n * NOC1 + ic) * 16 + kk]);
    }
}

// ---------------- K2: FUSED WavConv + PrimaryCaps conv ---------------------
// h2 never touches HBM (R11/R12: FETCH 39->15 MB, WRITE 55->37 MB).
// R13: wavconv MFMA computed TRANSPOSED via operand swap mfma(Bh, ah) =
// (A·B)^T — lane then holds 4 consecutive oc for one pos = 8 contiguous
// bytes of an A-row -> phase-1c is 16 ds_write_b64 (was 64 ds_write_b16,
// 5-7M bank conflicts). aslot() covers both the write and read patterns.
__global__ __launch_bounds__(512, 2) void k_wavcaps(
        const float* __restrict__ x,
        const short* __restrict__ bwh,
        const short* __restrict__ bph,
        const float* __restrict__ cb,
        float* __restrict__ u) {
    __shared__ char smem[66048];         // A: 258 rows x 256 B; xl+p_lds overlay
    short* Ald   = (short*)smem;         // swizzled [row][16B-slot]
    short* xl    = (short*)smem;         // [8][1512] overlay (dead before A writes)
    float* p_lds = (float*)smem;         // [8 b][1152] overlay (after conv loop)

    int tid  = threadIdx.x;
    int w    = tid >> 6;     // phase1: batch 0..7; phase2: oc-half quarter
    int lane = tid & 63;
    int col  = lane & 15;
    int rg   = lane >> 4;
    int b0   = blockIdx.x * 8;

    // ---- phase 1a: stage x -> xl fp16 (24 KB) ----
    for (int i4 = tid; i4 < 2016; i4 += 512) {
        int b  = i4 / 252;
        int e4 = i4 - b * 252;
        float4 v = *(const float4*)(x + (size_t)(b0 + b) * XLEN + e4 * 4);
        int i    = e4 * 4;
        int slot = i + 8 * (i >> 4);
        short4v hv;
        hv.x = f2h(v.x); hv.y = f2h(v.y); hv.z = f2h(v.z); hv.w = f2h(v.w);
        *(short4v*)&xl[(size_t)b * 1512 + slot] = hv;
    }
    __syncthreads();

    // ---- phase 1b: wavconv MFMA, operand-swapped (output transposed) ----
    {
        f32x4 acc[2][8];
        f32x4 z = {0.f, 0.f, 0.f, 0.f};
#pragma unroll
        for (int tl = 0; tl < 2; ++tl)
#pragma unroll
            for (int nt = 0; nt < 8; ++nt) acc[tl][nt] = z;

        for (int s = 0; s < 16; ++s) {
            half8 Bh[8];
#pragma unroll
            for (int nt = 0; nt < 8; ++nt) {
                size_t off = ((size_t)(nt * 16 + s) * 64 + lane) * 8;
                Bh[nt] = __builtin_bit_cast(half8, *(const short8*)(bwh + off));
            }
#pragma unroll
            for (int tl = 0; tl < 2; ++tl) {
                int pos  = tl * 16 + col;
                int i    = (pos + 2 * s) * 16 + rg * 8;
                int slot = i + 8 * (i >> 4);
                half8 ah = __builtin_bit_cast(half8, *(const short8*)&xl[(size_t)w * 1512 + slot]);
#pragma unroll
                for (int nt = 0; nt < 8; ++nt)
                    acc[tl][nt] = __builtin_amdgcn_mfma_f32_16x16x32_f16(Bh[nt], ah, acc[tl][nt], 0, 0, 0);
            }
        }
        __syncthreads();    // xl dead; A may overlay it now

        // ---- phase 1c: transposed acc -> swizzled A-LDS, b64 writes ----
        // lane holds: pos = tl*16 + col (the C-col), oc = nt*16 + rg*4 + r.
        // 4 r-values = 4 consecutive oc = one aligned 8-byte chunk-half.
#pragma unroll
        for (int tl = 0; tl < 2; ++tl) {
            int row = w * 32 + tl * 16 + col;        // row&15 == col
#pragma unroll
            for (int nt = 0; nt < 8; ++nt) {
                int ocb  = nt * 16 + rg * 4;         // 4 contiguous oc
                int slot = aslot(row, ocb >> 3);
                short4v hv;
                hv.x = f2h(acc[tl][nt][0]);
                hv.y = f2h(acc[tl][nt][1]);
                hv.z = f2h(acc[tl][nt][2]);
                hv.w = f2h(acc[tl][nt][3]);
                *(short4v*)&Ald[row * 128 + slot * 8 + (ocb & 7)] = hv;
            }
        }
        if (tid < 32) {                          // zero guard rows 256,257
            short8 zz = {0, 0, 0, 0, 0, 0, 0, 0};
            *(short8*)&Ald[4096 * 8 + tid * 8] = zz;
        }
    }
    __syncthreads();

    // ---- phase 2: conv main loop (R4 core, aslot read) ----
    f32x4 acc[5][2];
    f32x4 z = {0.f, 0.f, 0.f, 0.f};
#pragma unroll
    for (int mt = 0; mt < 5; ++mt) { acc[mt][0] = z; acc[mt][1] = z; }

    int rowb[5];
#pragma unroll
    for (int mt = 0; mt < 5; ++mt) {
        int m = mt * 16 + col;
        rowb[mt] = (m & 7) * 32 + 2 * (m >> 3);
    }

    for (int s = 0; s < 64; ++s) {
        int kk    = s >> 2;
        int icb8  = (s & 3) * 4;                 // base 16B-slot
        short8 ar[5];
#pragma unroll
        for (int mt = 0; mt < 5; ++mt) {
            int row  = rowb[mt] + kk;
            int slot = aslot(row, icb8 + rg);
            ar[mt] = *(const short8*)&Ald[row * 128 + slot * 8];
        }
#pragma unroll
        for (int n = 0; n < 2; ++n) {
            size_t bo = ((size_t)((w + n * 8) * 64 + s) * 64 + lane) * 8;
            half8 Bh = __builtin_bit_cast(half8, *(const short8*)(bph + bo));
#pragma unroll
            for (int mt = 0; mt < 5; ++mt)
                acc[mt][n] = __builtin_amdgcn_mfma_f32_16x16x32_f16(
                    __builtin_bit_cast(half8, ar[mt]), Bh, acc[mt][n], 0, 0, 0);
        }
    }
    __syncthreads();    // all A reads done before p_lds overlays the buffer

    int oc2l = w * 16 + col;                  // 0..127 within half
    for (int n = 0; n < 2; ++n) {
        float bias = cb[n * 128 + oc2l];
#pragma unroll
        for (int mt = 0; mt < 5; ++mt)
#pragma unroll
            for (int r = 0; r < 4; ++r) {
                int m = mt * 16 + rg * 4 + r;
                if (m < 72)
                    p_lds[(m & 7) * 1152 + oc2l * 9 + (m >> 3)] = acc[mt][n][r] + bias;
            }
        __syncthreads();
        for (int idx = tid; idx < 1152; idx += 512) {   // 8 b x 144 caps
            int lb = idx / 144;
            int cl = idx - lb * 144;
            float* ppt = &p_lds[lb * 1152 + cl * 8];
            float sn = 0.f;
#pragma unroll
            for (int i = 0; i < NDIM; ++i) sn = fmaf(ppt[i], ppt[i], sn);
            float sc = sn / (1.f + sn) / sqrtf(sn + 1e-8f);
            float* ug = u + ((size_t)(b0 + lb) * (NCAPS * NDIM) + (n * 144 + cl) * 8);
            float4 u0 = make_float4(ppt[0] * sc, ppt[1] * sc, ppt[2] * sc, ppt[3] * sc);
            float4 u1 = make_float4(ppt[4] * sc, ppt[5] * sc, ppt[6] * sc, ppt[7] * sc);
            ((float4*)ug)[0] = u0;
            ((float4*)ug)[1] = u1;
        }
        __syncthreads();
    }
}

// ---------------- K4: u_hat + routing, 2 batches/block, 1024 threads -------
// R1 version (proven 92.5 us, VGPR 32, no spill). LOCKED: R2 (scalar uh)
// scratch-spilled (+65MB writes); R6 (LDS atomicAdd) serialized on the LDS
// atomic unit (+50us); R9 (u transpose) 5x'd HBM fetch (299MB).
__global__ __launch_bounds__(1024, 8) void k_routing(const float* __restrict__ u,
                                                     const float* __restrict__ Wc,
                                                     float* __restrict__ out) {
    __shared__ float b_lds[2][NCAPS * 4];     // 9216 B
    __shared__ float c_lds[2][NCAPS * 4];     // 9216 B
    __shared__ float part_lds[2][1024];       // 8192 B
    __shared__ float v_lds[2][64];            // 512 B

    int tid = threadIdx.x;
    int b0  = blockIdx.x * 2;

    int g = tid >> 6;        // 0..15
    int l = tid & 63;
    int d = l >> 4;
    int o = l & 15;
    int gu = __builtin_amdgcn_readfirstlane(g);   // wave-uniform -> s_load for u

    const float* ub0 = u + (size_t)(b0 + 0) * (NCAPS * NDIM) + gu * 18 * NDIM;
    const float* ub1 = u + (size_t)(b0 + 1) * (NCAPS * NDIM) + gu * 18 * NDIM;

    f32x2 uh[18];
#pragma unroll
    for (int c = 0; c < 18; ++c) {
        int cap = gu * 18 + c;
        const float4* W4 = (const float4*)(Wc + ((size_t)cap * 512) + l * 8);
        float4 A  = W4[0];
        float4 Bv = W4[1];
        f32x2 u0 = {ub0[c * 8 + 0], ub1[c * 8 + 0]};
        f32x2 u1 = {ub0[c * 8 + 1], ub1[c * 8 + 1]};
        f32x2 u2 = {ub0[c * 8 + 2], ub1[c * 8 + 2]};
        f32x2 u3 = {ub0[c * 8 + 3], ub1[c * 8 + 3]};
        f32x2 u4 = {ub0[c * 8 + 4], ub1[c * 8 + 4]};
        f32x2 u5 = {ub0[c * 8 + 5], ub1[c * 8 + 5]};
        f32x2 u6 = {ub0[c * 8 + 6], ub1[c * 8 + 6]};
        f32x2 u7 = {ub0[c * 8 + 7], ub1[c * 8 + 7]};
        f32x2 t = (f32x2){A.x, A.x} * u0;
        t = pkfma(A.y,  u1, t);
        t = pkfma(A.z,  u2, t);
        t = pkfma(A.w,  u3, t);
        t = pkfma(Bv.x, u4, t);
        t = pkfma(Bv.y, u5, t);
        t = pkfma(Bv.z, u6, t);
        t = pkfma(Bv.w, u7, t);
        uh[c] = t;
    }

    for (int r = 0; r < 3; ++r) {
        if (r > 0) {
            __builtin_amdgcn_wave_barrier();
            for (int i = l; i < 36; i += 64) {       // 2 batches x 18 caps
                int bb = (i >= 18) ? 1 : 0;
                int cl = i - bb * 18;
                int c  = gu * 18 + cl;
                float4 bv = *(const float4*)&b_lds[bb][c * 4];
                float m  = fmaxf(fmaxf(bv.x, bv.y), fmaxf(bv.z, bv.w));
                float e0 = expf(bv.x - m), e1 = expf(bv.y - m);
                float e2 = expf(bv.z - m), e3 = expf(bv.w - m);
                float inv = 1.f / (e0 + e1 + e2 + e3);
                e0 *= inv; e1 *= inv; e2 *= inv; e3 *= inv;
                *(float4*)&c_lds[bb][c * 4] = make_float4(e0, e1, e2, e3);
                if (r == 2) {
                    *(float4*)(out + 16384 + ((size_t)(b0 + bb) * NCAPS + c) * 4) =
                        make_float4(e0, e1, e2, e3);
                }
            }
            __builtin_amdgcn_wave_barrier();
        }

        f32x2 p = {0.f, 0.f};
        if (r == 0) {
#pragma unroll
            for (int c = 0; c < 18; ++c)
                p = pkfma(0.25f, uh[c], p);
        } else {
#pragma unroll
            for (int c = 0; c < 18; ++c) {
                f32x2 c2 = {c_lds[0][(g * 18 + c) * 4 + d],
                            c_lds[1][(g * 18 + c) * 4 + d]};
                p = c2 * uh[c] + p;    // v_pk_fma_f32
            }
        }
        part_lds[0][tid] = p.x;
        part_lds[1][tid] = p.y;
        __syncthreads();

        if (tid < 128) {
            int bb = tid >> 6;
            int ll = tid & 63;
            float sv = 0.f;
#pragma unroll
            for (int k = 0; k < 16; ++k) sv += part_lds[bb][ll + 64 * k];
            float sq = rowsum16(sv * sv);
            float sc = sq / (1.f + sq) / sqrtf(sq + 1e-8f);
            float v  = sv * sc;
            v_lds[bb][ll] = v;
            if (r == 2) {
                float vv = rowsum16(v * v);
                if ((ll & 15) == 0)
                    out[(size_t)(b0 + bb) * 4 + (ll >> 4)] = sqrtf(vv);
            }
        }
        __syncthreads();

        if (r < 2) {
            f32x2 v01 = {v_lds[0][l], v_lds[1][l]};
#pragma unroll
            for (int c = 0; c < 18; ++c) {
                f32x2 t2 = uh[c] * v01;    // packed mul
                float t0 = rowsum16(t2.x);
                float t1 = rowsum16(t2.y);
                if (o == 0) {
                    if (r == 0) {
                        b_lds[0][(g * 18 + c) * 4 + d] = t0;
                        b_lds[1][(g * 18 + c) * 4 + d] = t1;
                    } else {
                        b_lds[0][(g * 18 + c) * 4 + d] += t0;
                        b_lds[1][(g * 18 + c) * 4 + d] += t1;
                    }
                }
            }
        }
    }
}

extern "C" void kernel_launch(void* const* d_in, const int* in_sizes, int n_in,
                              void* d_out, int out_size, void* d_ws, size_t ws_size,
                              hipStream_t stream) {
    const float* x      = (const float*)d_in[0];
    const float* a      = (const float*)d_in[1];
    const float* w      = (const float*)d_in[2];
    const float* conv_w = (const float*)d_in[3];
    const float* conv_b = (const float*)d_in[4];
    const float* W_caps = (const float*)d_in[5];
    float* out = (float*)d_out;
    char* ws   = (char*)d_ws;

    short*  bwh = (short*)(ws + BWH_OFF);
    short*  bph = (short*)(ws + BPH_OFF);
    float*  u   = (float*)(ws + U_OFF);

    k_pack<<<2304, 256, 0, stream>>>(a, w, conv_w, bwh, bph);
    k_wavcaps<<<BATCH / 8, 512, 0, stream>>>(x, bwh, bph, conv_b, u);
    k_routing<<<BATCH / 2, 1024, 0, stream>>>(u, W_caps, out);
}

// Round 14
// 226.716 us; speedup vs baseline: 1.1183x; 1.1121x over previous
//
#include <hip/hip_runtime.h>
#include <hip/hip_bf16.h>
#include <math.h>

typedef __attribute__((ext_vector_type(4))) short short4v;
typedef __attribute__((ext_vector_type(8))) short short8;
typedef __attribute__((ext_vector_type(4))) float f32x4;
typedef __attribute__((ext_vector_type(2))) float f32x2;
typedef _Float16 half8 __attribute__((ext_vector_type(8)));

#define BATCH   4096
#define XLEN    1008
#define NOC1    128
#define NPOS    32
#define NOC2    256
#define NQ      9
#define NCAPS   288
#define NDIM    8

// ws layout (bytes)
#define BWH_OFF   0           // wavelet B-pack fp16, 128 KB
#define BPH_OFF   131072      // conv2 B-pack fp16, 1 MB
#define H2_OFF    1179648     // h2 fp16 [b][pos32][ic128], 33.55 MB
#define U_OFF     34734080    // u fp32 [b][288][8], 37.75 MB

static __device__ __forceinline__ short f2h(float v) {
    _Float16 h = (_Float16)v;
    return *reinterpret_cast<short*>(&h);
}

// packed fp32 fma on batch-pairs: a (splat) * b + c  ->  v_pk_fma_f32
static __device__ __forceinline__ f32x2 pkfma(float a, f32x2 b, f32x2 c) {
    f32x2 av = {a, a};
    return av * b + c;    // clang: llvm.fmuladd<2 x float> -> v_pk_fma_f32
}

// DPP 16-lane (row) sum — VALU pipe. Bitwise == shfl_xor 1/2/4/8 tree.
template <int CTRL>
static __device__ __forceinline__ float dpp_addf(float x) {
    int y = __builtin_amdgcn_update_dpp(0, __builtin_bit_cast(int, x),
                                        CTRL, 0xf, 0xf, true);
    return x + __builtin_bit_cast(float, y);
}
static __device__ __forceinline__ float rowsum16(float x) {
    x = dpp_addf<0xB1>(x);    // quad_perm xor1
    x = dpp_addf<0x4E>(x);    // quad_perm xor2
    x = dpp_addf<0x141>(x);   // row_half_mirror
    x = dpp_addf<0x140>(x);   // row_mirror
    return x;
}

// ---------------- K1: fused weight packing (wavelet + conv2), fp16 ---------
__global__ __launch_bounds__(256) void k_pack(const float* __restrict__ a,
                                              const float* __restrict__ w,
                                              const float* __restrict__ cw,
                                              short* __restrict__ bwh,
                                              short* __restrict__ bph) {
    int bid = blockIdx.x;
    int tid = threadIdx.x;
    if (bid < 256) {
        int idx = bid * 256 + tid;            // 65536 wavelet elems
        int e    = idx & 7;
        int lane = (idx >> 3) & 63;
        int s    = (idx >> 9) & 15;
        int nt   = idx >> 13;
        int oc = nt * 16 + (lane & 15);
        int k  = s * 32 + (lane >> 4) * 8 + e;
        float t  = -1.0f + 2.0f * (float)k / 511.0f;
        float av = fmaxf(a[oc], 1e-5f);
        float ts = t / av;
        bwh[idx] = f2h(cosf(w[oc] * t) * expf(-0.5f * ts * ts));
    } else {
        int o = (bid - 256) * 256 + tid;      // 524288 conv2 elems
        int e    = o & 7;
        int lane = (o >> 3) & 63;
        int s    = (o >> 9) & 63;
        int nt   = o >> 15;
        int n  = nt * 16 + (lane & 15);
        int j  = lane >> 4;
        int kk = s >> 2;
        int ic = (s & 3) * 32 + j * 8 + e;
        bph[o] = f2h(cw[(n * NOC1 + ic) * 16 + kk]);
    }
}

// ---------------- K2: WavConv via single fp16 MFMA (best-measured form) ----
__global__ __launch_bounds__(256, 2) void k_wavconv_mfma(
        const float* __restrict__ x,
        const short* __restrict__ bwh,
        short* __restrict__ h2) {
    __shared__ short xl[8][1512];   // 24192 B; slot(i) = i + 8*(i>>4)

    int tid = threadIdx.x;
    int b0  = blockIdx.x * 8;

    for (int i4 = tid; i4 < 2016; i4 += 256) {
        int b  = i4 / 252;
        int e4 = i4 - b * 252;
        float4 v = *(const float4*)(x + (size_t)(b0 + b) * XLEN + e4 * 4);
        int i    = e4 * 4;
        int slot = i + 8 * (i >> 4);
        short4v hv;
        hv.x = f2h(v.x); hv.y = f2h(v.y); hv.z = f2h(v.z); hv.w = f2h(v.w);
        *(short4v*)&xl[b][slot] = hv;
    }
    __syncthreads();

    int lane = tid & 63;
    int w    = tid >> 6;     // 0..3
    int col  = lane & 15;
    int rg   = lane >> 4;    // 0..3

    f32x4 acc[4][8];
    f32x4 z = {0.f, 0.f, 0.f, 0.f};
#pragma unroll
    for (int tl = 0; tl < 4; ++tl)
#pragma unroll
        for (int nt = 0; nt < 8; ++nt) acc[tl][nt] = z;

    for (int s = 0; s < 16; ++s) {
        half8 Bh[8];
#pragma unroll
        for (int nt = 0; nt < 8; ++nt) {
            size_t off = ((size_t)(nt * 16 + s) * 64 + lane) * 8;
            Bh[nt] = __builtin_bit_cast(half8, *(const short8*)(bwh + off));
        }
#pragma unroll
        for (int tl = 0; tl < 4; ++tl) {
            int mt  = 4 * w + tl;
            int bl  = mt >> 1;
            int pos = (mt & 1) * 16 + col;
            int i    = (pos + 2 * s) * 16 + rg * 8;
            int slot = i + 8 * (i >> 4);
            half8 ah = __builtin_bit_cast(half8, *(const short8*)&xl[bl][slot]);
#pragma unroll
            for (int nt = 0; nt < 8; ++nt)
                acc[tl][nt] = __builtin_amdgcn_mfma_f32_16x16x32_f16(ah, Bh[nt], acc[tl][nt], 0, 0, 0);
        }
    }

#pragma unroll
    for (int tl = 0; tl < 4; ++tl) {
        int mt = 4 * w + tl;
        int b  = b0 + (mt >> 1);
        int ph = (mt & 1) * 16;
#pragma unroll
        for (int nt = 0; nt < 8; ++nt) {
            int oc = nt * 16 + col;
#pragma unroll
            for (int r = 0; r < 4; ++r) {
                int pos = ph + rg * 4 + r;
                h2[((size_t)b * NPOS + pos) * NOC1 + oc] = f2h(acc[tl][nt][r]);
            }
        }
    }
}

// ---------------- K3: PrimaryCaps conv, full-A prestage (best-measured) ----
// Per-block A (8-batch h2 slice) = 64 KB staged in LDS once (swizzled),
// 64 K-steps, zero barriers, ROLLED loop. LOCKED findings: R5/R7 manual
// prefetch regressed; R9 u-transpose 5x'd HBM fetch; R11-R13 fusion traded
// 10us of HBM traffic for >20us of LDS-conflict stalls.
__global__ __launch_bounds__(512, 4) void k_conv_mfma(const short* __restrict__ h2,
                                                      const short* __restrict__ bph,
                                                      const float* __restrict__ cb,
                                                      float* __restrict__ u) {
    __shared__ char smem[66048];         // 258 rows x 256 B (A), epilogue overlay
    short* Ald   = (short*)smem;         // swizzled [row][16B-slot]
    float* p_lds = (float*)smem;         // [8 b][1152], reused after loop

    int tid  = threadIdx.x;
    int w    = tid >> 6;
    int lane = tid & 63;
    int col  = lane & 15;
    int rg   = lane >> 4;
    int b0   = blockIdx.x * 8;

    // ---- stage all of A (64 KB), swizzled ----
    {
        const short8* src = (const short8*)(h2 + (size_t)b0 * NPOS * NOC1);
#pragma unroll
        for (int i = 0; i < 8; ++i) {
            int g    = tid + 512 * i;            // 16B chunk id, 0..4095
            short8 v = src[g];
            int row  = g >> 4;
            int slot = (g & 15) ^ ((row >> 5) & 7);
            *(short8*)&Ald[row * 128 + slot * 8] = v;
        }
        if (tid < 32) {                          // zero guard rows 256,257 (f=0)
            short8 zz = {0, 0, 0, 0, 0, 0, 0, 0};
            *(short8*)&Ald[4096 * 8 + tid * 8] = zz;
        }
    }
    __syncthreads();

    f32x4 acc[5][2];
    f32x4 z = {0.f, 0.f, 0.f, 0.f};
#pragma unroll
    for (int mt = 0; mt < 5; ++mt) { acc[mt][0] = z; acc[mt][1] = z; }

    // per-lane per-mt row base: (m&7)*32 + 2*(m>>3), m = mt*16+col
    int rowb[5];
#pragma unroll
    for (int mt = 0; mt < 5; ++mt) {
        int m = mt * 16 + col;
        rowb[mt] = (m & 7) * 32 + 2 * (m >> 3);
    }

    for (int s = 0; s < 64; ++s) {
        int kk    = s >> 2;
        int icb8  = (s & 3) * 4;                 // icb/8: base 16B-slot
        short8 ar[5];
#pragma unroll
        for (int mt = 0; mt < 5; ++mt) {
            int row  = rowb[mt] + kk;
            int slot = (icb8 + rg) ^ ((row >> 5) & 7);
            ar[mt] = *(const short8*)&Ald[row * 128 + slot * 8];
        }
#pragma unroll
        for (int n = 0; n < 2; ++n) {
            size_t bo = ((size_t)((w + n * 8) * 64 + s) * 64 + lane) * 8;
            half8 Bh = __builtin_bit_cast(half8, *(const short8*)(bph + bo));
#pragma unroll
            for (int mt = 0; mt < 5; ++mt)
                acc[mt][n] = __builtin_amdgcn_mfma_f32_16x16x32_f16(
                    __builtin_bit_cast(half8, ar[mt]), Bh, acc[mt][n], 0, 0, 0);
        }
    }
    __syncthreads();    // all A reads done before p_lds overlays the buffer

    int oc2l = w * 16 + col;                  // 0..127 within half
    for (int n = 0; n < 2; ++n) {
        float bias = cb[n * 128 + oc2l];
#pragma unroll
        for (int mt = 0; mt < 5; ++mt)
#pragma unroll
            for (int r = 0; r < 4; ++r) {
                int m = mt * 16 + rg * 4 + r;
                if (m < 72)
                    p_lds[(m & 7) * 1152 + oc2l * 9 + (m >> 3)] = acc[mt][n][r] + bias;
            }
        __syncthreads();
        for (int idx = tid; idx < 1152; idx += 512) {   // 8 b x 144 caps
            int lb = idx / 144;
            int cl = idx - lb * 144;
            float* ppt = &p_lds[lb * 1152 + cl * 8];
            float sn = 0.f;
#pragma unroll
            for (int i = 0; i < NDIM; ++i) sn = fmaf(ppt[i], ppt[i], sn);
            float sc = sn / (1.f + sn) / sqrtf(sn + 1e-8f);
            float* ug = u + ((size_t)(b0 + lb) * (NCAPS * NDIM) + (n * 144 + cl) * 8);
            float4 u0 = make_float4(ppt[0] * sc, ppt[1] * sc, ppt[2] * sc, ppt[3] * sc);
            float4 u1 = make_float4(ppt[4] * sc, ppt[5] * sc, ppt[6] * sc, ppt[7] * sc);
            ((float4*)ug)[0] = u0;
            ((float4*)ug)[1] = u1;
        }
        __syncthreads();
    }
}

// ---------------- K4: u_hat + routing, 2 batches/block, 1024 threads -------
// R1 version (proven 92.5 us, VGPR 32, no spill). LOCKED: R2 (scalar uh)
// scratch-spilled (+65MB writes); R6 (LDS atomicAdd) serialized on the LDS
// atomic unit (+50us); R9 (u transpose) 5x'd HBM fetch (299MB).
__global__ __launch_bounds__(1024, 8) void k_routing(const float* __restrict__ u,
                                                     const float* __restrict__ Wc,
                                                     float* __restrict__ out) {
    __shared__ float b_lds[2][NCAPS * 4];     // 9216 B
    __shared__ float c_lds[2][NCAPS * 4];     // 9216 B
    __shared__ float part_lds[2][1024];       // 8192 B
    __shared__ float v_lds[2][64];            // 512 B

    int tid = threadIdx.x;
    int b0  = blockIdx.x * 2;

    int g = tid >> 6;        // 0..15
    int l = tid & 63;
    int d = l >> 4;
    int o = l & 15;
    int gu = __builtin_amdgcn_readfirstlane(g);   // wave-uniform -> s_load for u

    const float* ub0 = u + (size_t)(b0 + 0) * (NCAPS * NDIM) + gu * 18 * NDIM;
    const float* ub1 = u + (size_t)(b0 + 1) * (NCAPS * NDIM) + gu * 18 * NDIM;

    f32x2 uh[18];
#pragma unroll
    for (int c = 0; c < 18; ++c) {
        int cap = gu * 18 + c;
        const float4* W4 = (const float4*)(Wc + ((size_t)cap * 512) + l * 8);
        float4 A  = W4[0];
        float4 Bv = W4[1];
        f32x2 u0 = {ub0[c * 8 + 0], ub1[c * 8 + 0]};
        f32x2 u1 = {ub0[c * 8 + 1], ub1[c * 8 + 1]};
        f32x2 u2 = {ub0[c * 8 + 2], ub1[c * 8 + 2]};
        f32x2 u3 = {ub0[c * 8 + 3], ub1[c * 8 + 3]};
        f32x2 u4 = {ub0[c * 8 + 4], ub1[c * 8 + 4]};
        f32x2 u5 = {ub0[c * 8 + 5], ub1[c * 8 + 5]};
        f32x2 u6 = {ub0[c * 8 + 6], ub1[c * 8 + 6]};
        f32x2 u7 = {ub0[c * 8 + 7], ub1[c * 8 + 7]};
        f32x2 t = (f32x2){A.x, A.x} * u0;
        t = pkfma(A.y,  u1, t);
        t = pkfma(A.z,  u2, t);
        t = pkfma(A.w,  u3, t);
        t = pkfma(Bv.x, u4, t);
        t = pkfma(Bv.y, u5, t);
        t = pkfma(Bv.z, u6, t);
        t = pkfma(Bv.w, u7, t);
        uh[c] = t;
    }

    for (int r = 0; r < 3; ++r) {
        if (r > 0) {
            __builtin_amdgcn_wave_barrier();
            for (int i = l; i < 36; i += 64) {       // 2 batches x 18 caps
                int bb = (i >= 18) ? 1 : 0;
                int cl = i - bb * 18;
                int c  = gu * 18 + cl;
                float4 bv = *(const float4*)&b_lds[bb][c * 4];
                float m  = fmaxf(fmaxf(bv.x, bv.y), fmaxf(bv.z, bv.w));
                float e0 = expf(bv.x - m), e1 = expf(bv.y - m);
                float e2 = expf(bv.z - m), e3 = expf(bv.w - m);
                float inv = 1.f / (e0 + e1 + e2 + e3);
                e0 *= inv; e1 *= inv; e2 *= inv; e3 *= inv;
                *(float4*)&c_lds[bb][c * 4] = make_float4(e0, e1, e2, e3);
                if (r == 2) {
                    *(float4*)(out + 16384 + ((size_t)(b0 + bb) * NCAPS + c) * 4) =
                        make_float4(e0, e1, e2, e3);
                }
            }
            __builtin_amdgcn_wave_barrier();
        }

        f32x2 p = {0.f, 0.f};
        if (r == 0) {
#pragma unroll
            for (int c = 0; c < 18; ++c)
                p = pkfma(0.25f, uh[c], p);
        } else {
#pragma unroll
            for (int c = 0; c < 18; ++c) {
                f32x2 c2 = {c_lds[0][(g * 18 + c) * 4 + d],
                            c_lds[1][(g * 18 + c) * 4 + d]};
                p = c2 * uh[c] + p;    // v_pk_fma_f32
            }
        }
        part_lds[0][tid] = p.x;
        part_lds[1][tid] = p.y;
        __syncthreads();

        if (tid < 128) {
            int bb = tid >> 6;
            int ll = tid & 63;
            float sv = 0.f;
#pragma unroll
            for (int k = 0; k < 16; ++k) sv += part_lds[bb][ll + 64 * k];
            float sq = rowsum16(sv * sv);
            float sc = sq / (1.f + sq) / sqrtf(sq + 1e-8f);
            float v  = sv * sc;
            v_lds[bb][ll] = v;
            if (r == 2) {
                float vv = rowsum16(v * v);
                if ((ll & 15) == 0)
                    out[(size_t)(b0 + bb) * 4 + (ll >> 4)] = sqrtf(vv);
            }
        }
        __syncthreads();

        if (r < 2) {
            f32x2 v01 = {v_lds[0][l], v_lds[1][l]};
#pragma unroll
            for (int c = 0; c < 18; ++c) {
                f32x2 t2 = uh[c] * v01;    // packed mul
                float t0 = rowsum16(t2.x);
                float t1 = rowsum16(t2.y);
                if (o == 0) {
                    if (r == 0) {
                        b_lds[0][(g * 18 + c) * 4 + d] = t0;
                        b_lds[1][(g * 18 + c) * 4 + d] = t1;
                    } else {
                        b_lds[0][(g * 18 + c) * 4 + d] += t0;
                        b_lds[1][(g * 18 + c) * 4 + d] += t1;
                    }
                }
            }
        }
    }
}

extern "C" void kernel_launch(void* const* d_in, const int* in_sizes, int n_in,
                              void* d_out, int out_size, void* d_ws, size_t ws_size,
                              hipStream_t stream) {
    const float* x      = (const float*)d_in[0];
    const float* a      = (const float*)d_in[1];
    const float* w      = (const float*)d_in[2];
    const float* conv_w = (const float*)d_in[3];
    const float* conv_b = (const float*)d_in[4];
    const float* W_caps = (const float*)d_in[5];
    float* out = (float*)d_out;
    char* ws   = (char*)d_ws;

    short*  bwh = (short*)(ws + BWH_OFF);
    short*  bph = (short*)(ws + BPH_OFF);
    short*  h2  = (short*)(ws + H2_OFF);
    float*  u   = (float*)(ws + U_OFF);

    k_pack<<<2304, 256, 0, stream>>>(a, w, conv_w, bwh, bph);
    k_wavconv_mfma<<<BATCH / 8, 256, 0, stream>>>(x, bwh, h2);
    k_conv_mfma<<<BATCH / 8, 512, 0, stream>>>(h2, bph, conv_b, u);
    k_routing<<<BATCH / 2, 1024, 0, stream>>>(u, W_caps, out);
}